// Round 9
// baseline (499.137 us; speedup 1.0000x reference)
//
#include <hip/hip_runtime.h>
#include <hip/hip_bf16.h>
#include <cstdint>

#define N_NODES 100000
#define N_EDGES 1600000
#define DIM 128            // HEADS * OUT_C = 4 * 32
#define GR 32              // rows per block in the dual GEMM
#define GEMM_BLOCKS (N_NODES / GR)          // 3125
#define HIST_BLOCKS 512                     // grid-stride, int4 loads

// branch-free exact LeakyReLU(0.2): v>=0 -> v, v<0 -> 0.2v
__device__ __forceinline__ float lr(float v) { return fmaxf(v, 0.2f * v); }

// ---------------------------------------------------------------------------
// Fused: dual projection + dst histogram (data-independent, co-scheduled).
// GEMM blocks: xl = x@Wl + bl (ws), xr = x@Wr + br (d_out as scratch; gat
//   wave d reads xr row d before overwriting with out row d). LDS-staged
//   32x256 tile; acc[8][4] live; W loads software-pipelined (next-iteration
//   prefetch, unroll-4 rotation) so L2 latency hides under the 128 fma/iter.
// Hist blocks (last 512): grid-stride deg histogram, int4-vectorized dst.
// ---------------------------------------------------------------------------
__global__ __launch_bounds__(256) void gemm_hist(
    const float* __restrict__ x,
    const float* __restrict__ Wl, const float* __restrict__ bl,
    const float* __restrict__ Wr, const float* __restrict__ br,
    float* __restrict__ xl, float* __restrict__ xr,
    const int* __restrict__ dst, int* __restrict__ deg) {
  __shared__ float xs[GR][DIM];          // 16 KB (unused by hist blocks)
  const int tid = threadIdx.x;

  if (blockIdx.x >= GEMM_BLOCKS) {       // block-uniform branch
    const int4* __restrict__ dst4 = reinterpret_cast<const int4*>(dst);
    const int stride = HIST_BLOCKS * 256;
    for (int i = (blockIdx.x - GEMM_BLOCKS) * 256 + tid;
         i < N_EDGES / 4; i += stride) {          // 1.6M/4 = 400000 exact
      const int4 d4 = dst4[i];
      atomicAdd(&deg[d4.x], 1);
      atomicAdd(&deg[d4.y], 1);
      atomicAdd(&deg[d4.z], 1);
      atomicAdd(&deg[d4.w], 1);
    }
    return;
  }

  const int row0 = blockIdx.x * GR;

  // stage x tile: 32 rows * 32 float4 = 1024 float4, 4 per thread, coalesced
#pragma unroll
  for (int i = 0; i < 4; ++i) {
    const int idx = i * 256 + tid;       // 0..1023
    const int r = idx >> 5;              // 32 float4 per row
    const int c4 = idx & 31;
    const float4 v = *reinterpret_cast<const float4*>(
        x + (size_t)(row0 + r) * DIM + c4 * 4);
    *reinterpret_cast<float4*>(&xs[r][c4 * 4]) = v;
  }
  __syncthreads();

  const int cg = tid & 63;               // 0..63 column group
  const int rg = tid >> 6;               // 0..3 row group
  const int which = cg >> 5;             // 0 -> Wl, 1 -> Wr
  const int col0 = (cg & 31) * 4;        // 0..124
  const float* __restrict__ W = which ? Wr : Wl;
  const float* __restrict__ b = which ? br : bl;
  float* __restrict__ o = which ? xr : xl;
  const int r0 = rg * 8;

  float acc[8][4];
#pragma unroll
  for (int r = 0; r < 8; ++r)
#pragma unroll
    for (int c = 0; c < 4; ++c) acc[r][c] = 0.f;

  // software-pipelined W loads: current regs wa*, prefetch wb* for kb+4
  float4 wa0 = *reinterpret_cast<const float4*>(W + 0 * DIM + col0);
  float4 wa1 = *reinterpret_cast<const float4*>(W + 1 * DIM + col0);
  float4 wa2 = *reinterpret_cast<const float4*>(W + 2 * DIM + col0);
  float4 wa3 = *reinterpret_cast<const float4*>(W + 3 * DIM + col0);

#pragma unroll 4
  for (int kb = 0; kb < DIM; kb += 4) {
    const int kn = (kb + 4 < DIM) ? kb + 4 : kb;   // clamp: last iter reloads (L1 hit)
    const float4 wb0 = *reinterpret_cast<const float4*>(W + (kn + 0) * DIM + col0);
    const float4 wb1 = *reinterpret_cast<const float4*>(W + (kn + 1) * DIM + col0);
    const float4 wb2 = *reinterpret_cast<const float4*>(W + (kn + 2) * DIM + col0);
    const float4 wb3 = *reinterpret_cast<const float4*>(W + (kn + 3) * DIM + col0);
#pragma unroll
    for (int r = 0; r < 8; ++r) {
      const float4 xv = *reinterpret_cast<const float4*>(&xs[r0 + r][kb]);
      acc[r][0] = fmaf(xv.x, wa0.x, acc[r][0]);
      acc[r][1] = fmaf(xv.x, wa0.y, acc[r][1]);
      acc[r][2] = fmaf(xv.x, wa0.z, acc[r][2]);
      acc[r][3] = fmaf(xv.x, wa0.w, acc[r][3]);
      acc[r][0] = fmaf(xv.y, wa1.x, acc[r][0]);
      acc[r][1] = fmaf(xv.y, wa1.y, acc[r][1]);
      acc[r][2] = fmaf(xv.y, wa1.z, acc[r][2]);
      acc[r][3] = fmaf(xv.y, wa1.w, acc[r][3]);
      acc[r][0] = fmaf(xv.z, wa2.x, acc[r][0]);
      acc[r][1] = fmaf(xv.z, wa2.y, acc[r][1]);
      acc[r][2] = fmaf(xv.z, wa2.z, acc[r][2]);
      acc[r][3] = fmaf(xv.z, wa2.w, acc[r][3]);
      acc[r][0] = fmaf(xv.w, wa3.x, acc[r][0]);
      acc[r][1] = fmaf(xv.w, wa3.y, acc[r][1]);
      acc[r][2] = fmaf(xv.w, wa3.z, acc[r][2]);
      acc[r][3] = fmaf(xv.w, wa3.w, acc[r][3]);
    }
    wa0 = wb0; wa1 = wb1; wa2 = wb2; wa3 = wb3;
  }

  const float4 bb = *reinterpret_cast<const float4*>(b + col0);
#pragma unroll
  for (int r = 0; r < 8; ++r) {
    float4 ov;
    ov.x = acc[r][0] + bb.x;
    ov.y = acc[r][1] + bb.y;
    ov.z = acc[r][2] + bb.z;
    ov.w = acc[r][3] + bb.w;
    *reinterpret_cast<float4*>(o + (size_t)(row0 + r0 + r) * DIM + col0) = ov;
  }
}

// ---------------------------------------------------------------------------
// CSR build. scan1: per-1024-block local exclusive scan of deg (-> loc) +
// block sums. scan2: exclusive scan of the 98 block sums. No scan3: scatter
// and gat apply bsum themselves.
// ---------------------------------------------------------------------------
__global__ __launch_bounds__(1024) void scan1(const int* __restrict__ deg,
                                              int* __restrict__ loc,
                                              int* __restrict__ bsum) {
  __shared__ int tmp[1024];
  const int tid = threadIdx.x;
  const int gid = blockIdx.x * 1024 + tid;
  const int v = (gid < N_NODES) ? deg[gid] : 0;
  int xacc = v;
  tmp[tid] = v;
  __syncthreads();
  for (int offd = 1; offd < 1024; offd <<= 1) {
    const int t = (tid >= offd) ? tmp[tid - offd] : 0;
    __syncthreads();
    xacc += t;
    tmp[tid] = xacc;
    __syncthreads();
  }
  if (gid < N_NODES) loc[gid] = xacc - v;        // exclusive within block
  if (tid == 1023) bsum[blockIdx.x] = xacc;      // block total
}

__global__ __launch_bounds__(128) void scan2(int* __restrict__ bsum, int nb) {
  __shared__ int tmp[128];
  const int tid = threadIdx.x;
  const int v = (tid < nb) ? bsum[tid] : 0;
  int xacc = v;
  tmp[tid] = v;
  __syncthreads();
  for (int offd = 1; offd < 128; offd <<= 1) {
    const int t = (tid >= offd) ? tmp[tid - offd] : 0;
    __syncthreads();
    xacc += t;
    tmp[tid] = xacc;
    __syncthreads();
  }
  if (tid < nb) bsum[tid] = xacc - v;            // exclusive block offsets
}

// scatter: csr slot = (local excl via atomic) + block offset. After this,
// loc[d] = local_excl[d] + deg[d]  (used by gat to reconstruct beg/end).
__global__ __launch_bounds__(256) void scatter_kernel(const int* __restrict__ src,
                                                      const int* __restrict__ dst,
                                                      int* __restrict__ loc,
                                                      const int* __restrict__ bsum,
                                                      int* __restrict__ csr) {
  const int4* __restrict__ src4 = reinterpret_cast<const int4*>(src);
  const int4* __restrict__ dst4 = reinterpret_cast<const int4*>(dst);
  const int i = blockIdx.x * 256 + threadIdx.x;
  if (i < N_EDGES / 4) {                         // 400000 exact
    const int4 s4 = src4[i];
    const int4 d4 = dst4[i];
    int slot;
    slot = atomicAdd(&loc[d4.x], 1) + bsum[d4.x >> 10];  csr[slot] = s4.x;
    slot = atomicAdd(&loc[d4.y], 1) + bsum[d4.y >> 10];  csr[slot] = s4.y;
    slot = atomicAdd(&loc[d4.z], 1) + bsum[d4.z >> 10];  csr[slot] = s4.z;
    slot = atomicAdd(&loc[d4.w], 1) + bsum[d4.w >> 10];  csr[slot] = s4.w;
  }
}

// ---------------------------------------------------------------------------
// One wave per destination node, 4-way edge packing:
// lane = q*16 + i (q = edge slot 0..3, i = channel group). Lane owns 8
// channels c0 = 8i .. 8i+7, so 16 lanes cover a 128-ch row and the wave
// processes FOUR edges per iteration (slot q handles edges 4j+q of the
// 64-id chunk). Head = 32 ch = 4 lanes -> score reduce is 2 shfl_xor (1,2).
// Four independent online-softmax states (m, l, acc8), merged at the end
// via shfl_xor 16 then 32. Self loop lives in slot 0 only. Invalid slots:
// score -2e30 (< -1e30 empty-state init -> exp underflows to 0) + w=0.
// CSR range from post-scatter loc: end = loc[d]+bsum[d>>10], beg = end-deg[d].
// xr lives in `out` (read before overwrite, same row only).
// ---------------------------------------------------------------------------
__global__ __launch_bounds__(256) void gat_node(
    const float* __restrict__ xl,
    const float* __restrict__ att, const float* __restrict__ bias,
    const int* __restrict__ loc, const int* __restrict__ deg,
    const int* __restrict__ bsum, const int* __restrict__ csr,
    float* __restrict__ out) {
  const int wid = (blockIdx.x * 256 + threadIdx.x) >> 6;
  const int lane = threadIdx.x & 63;
  if (wid >= N_NODES) return;
  const int d = wid;
  const int q = lane >> 4;           // edge slot
  const int i = lane & 15;           // channel group
  const int c0 = i * 8;              // channel base

  const float4 aA = *reinterpret_cast<const float4*>(att + c0);
  const float4 aB = *reinterpret_cast<const float4*>(att + c0 + 4);
  const float4 rA = *reinterpret_cast<const float4*>(out + (size_t)d * DIM + c0);
  const float4 rB = *reinterpret_cast<const float4*>(out + (size_t)d * DIM + c0 + 4);
  const float4 sA = *reinterpret_cast<const float4*>(xl + (size_t)d * DIM + c0);
  const float4 sB = *reinterpret_cast<const float4*>(xl + (size_t)d * DIM + c0 + 4);

  // self-loop score (same value in every slot; only slot 0 keeps the state)
  float p = lr(sA.x + rA.x) * aA.x + lr(sA.y + rA.y) * aA.y
          + lr(sA.z + rA.z) * aA.z + lr(sA.w + rA.w) * aA.w
          + lr(sB.x + rB.x) * aB.x + lr(sB.y + rB.y) * aB.y
          + lr(sB.z + rB.z) * aB.z + lr(sB.w + rB.w) * aB.w;
  p += __shfl_xor(p, 1);
  p += __shfl_xor(p, 2);             // 4-lane head group holds its score

  const bool q0 = (q == 0);
  float m = q0 ? p : -1e30f;         // running max
  float l = q0 ? 1.f : 0.f;          // running denom
  float4 cA, cB;                     // running weighted message sum
  cA.x = q0 ? sA.x : 0.f;  cA.y = q0 ? sA.y : 0.f;
  cA.z = q0 ? sA.z : 0.f;  cA.w = q0 ? sA.w : 0.f;
  cB.x = q0 ? sB.x : 0.f;  cB.y = q0 ? sB.y : 0.f;
  cB.z = q0 ? sB.z : 0.f;  cB.w = q0 ? sB.w : 0.f;

  const int dg = deg[d];
  const int end = loc[d] + bsum[d >> 10];   // loc[d] = local_excl + deg (post-scatter)
  const int beg = end - dg;

  for (int cbase = beg; cbase < end; cbase += 64) {
    const int idx = cbase + lane;
    const int sv = csr[idx < end ? idx : end - 1];   // 64 edge ids, coalesced
    const int cnt = min(64, end - cbase);
    const int nj = (cnt + 3) >> 2;   // iterations; slot q handles edges 4j+q

    // prefetch j=0: slot q's first edge id is at position q
    const int s0 = __shfl(sv, q);
    const float* rp0 = xl + (size_t)s0 * DIM + c0;
    float4 nA = *reinterpret_cast<const float4*>(rp0);
    float4 nB = *reinterpret_cast<const float4*>(rp0 + 4);

    for (int j = 0; j < nj; ++j) {
      const float4 xA = nA;
      const float4 xB = nB;
      if (j + 1 < nj) {
        const int s1 = __shfl(sv, 4 * (j + 1) + q);  // <= 63 always
        const float* rp = xl + (size_t)s1 * DIM + c0;
        nA = *reinterpret_cast<const float4*>(rp);
        nB = *reinterpret_cast<const float4*>(rp + 4);
      }
      const bool valid = (4 * j + q) < cnt;

      float ek = lr(xA.x + rA.x) * aA.x + lr(xA.y + rA.y) * aA.y
               + lr(xA.z + rA.z) * aA.z + lr(xA.w + rA.w) * aA.w
               + lr(xB.x + rB.x) * aB.x + lr(xB.y + rB.y) * aB.y
               + lr(xB.z + rB.z) * aB.z + lr(xB.w + rB.w) * aB.w;
      ek += __shfl_xor(ek, 1);
      ek += __shfl_xor(ek, 2);
      ek = valid ? ek : -2e30f;

      const float mn = fmaxf(m, ek);
      const float sc = __expf(m - mn);
      float w = __expf(ek - mn);
      w = valid ? w : 0.f;
      l = l * sc + w;
      cA.x = fmaf(cA.x, sc, w * xA.x);
      cA.y = fmaf(cA.y, sc, w * xA.y);
      cA.z = fmaf(cA.z, sc, w * xA.z);
      cA.w = fmaf(cA.w, sc, w * xA.w);
      cB.x = fmaf(cB.x, sc, w * xB.x);
      cB.y = fmaf(cB.y, sc, w * xB.y);
      cB.z = fmaf(cB.z, sc, w * xB.z);
      cB.w = fmaf(cB.w, sc, w * xB.w);
      m = mn;
    }
  }

  // merge the four slots' states: xor 16 (q0<->q1, q2<->q3), then xor 32
  auto merge = [&](int mask) {
    const float mo = __shfl_xor(m, mask);
    const float lo = __shfl_xor(l, mask);
    float4 oA, oB;
    oA.x = __shfl_xor(cA.x, mask);  oA.y = __shfl_xor(cA.y, mask);
    oA.z = __shfl_xor(cA.z, mask);  oA.w = __shfl_xor(cA.w, mask);
    oB.x = __shfl_xor(cB.x, mask);  oB.y = __shfl_xor(cB.y, mask);
    oB.z = __shfl_xor(cB.z, mask);  oB.w = __shfl_xor(cB.w, mask);
    const float ms = fmaxf(m, mo);
    const float w1 = __expf(m - ms);
    const float w2 = __expf(mo - ms);
    l = l * w1 + lo * w2;
    cA.x = cA.x * w1 + oA.x * w2;  cA.y = cA.y * w1 + oA.y * w2;
    cA.z = cA.z * w1 + oA.z * w2;  cA.w = cA.w * w1 + oA.w * w2;
    cB.x = cB.x * w1 + oB.x * w2;  cB.y = cB.y * w1 + oB.y * w2;
    cB.z = cB.z * w1 + oB.z * w2;  cB.w = cB.w * w1 + oB.w * w2;
    m = ms;
  };
  merge(16);
  merge(32);

  if (lane < 16) {                   // slot 0 writes the result
    const float inv = 1.f / l;       // l >= e^{p - m*} > 0 (self loop)
    const float4 bA = *reinterpret_cast<const float4*>(bias + c0);
    const float4 bB = *reinterpret_cast<const float4*>(bias + c0 + 4);
    float4 oA, oB;
    oA.x = cA.x * inv + bA.x;  oA.y = cA.y * inv + bA.y;
    oA.z = cA.z * inv + bA.z;  oA.w = cA.w * inv + bA.w;
    oB.x = cB.x * inv + bB.x;  oB.y = cB.y * inv + bB.y;
    oB.z = cB.z * inv + bB.z;  oB.w = cB.w * inv + bB.w;
    *reinterpret_cast<float4*>(out + (size_t)d * DIM + c0) = oA;
    *reinterpret_cast<float4*>(out + (size_t)d * DIM + c0 + 4) = oB;
  }
}

// ---------------------------------------------------------------------------
extern "C" void kernel_launch(void* const* d_in, const int* in_sizes, int n_in,
                              void* d_out, int out_size, void* d_ws, size_t ws_size,
                              hipStream_t stream) {
  const float* x    = (const float*)d_in[0];
  const float* Wl   = (const float*)d_in[1];
  const float* bl   = (const float*)d_in[2];
  const float* Wr   = (const float*)d_in[3];
  const float* br   = (const float*)d_in[4];
  const float* att  = (const float*)d_in[5];
  const float* bias = (const float*)d_in[6];
  const int* src    = (const int*)d_in[7];
  const int* dst    = (const int*)d_in[8];
  float* out = (float*)d_out;

  char* w = (char*)d_ws;
  size_t off = 0;
  auto alloc = [&](size_t bytes) -> void* {
    void* p = w + off;
    off = (off + bytes + 255) & ~(size_t)255;
    return p;
  };
  float* xl = (float*)alloc((size_t)N_NODES * DIM * 4);   // 51.2 MB
  int* deg  = (int*)alloc((size_t)N_NODES * 4);
  int* loc  = (int*)alloc((size_t)N_NODES * 4);
  int* bsum = (int*)alloc(1024);
  int* csr  = (int*)alloc((size_t)N_EDGES * 4);           // 6.4 MB
  float* xr = out;                                        // scratch alias (safe: see gat_node)

  const int nscan_blocks = (N_NODES + 1023) / 1024;   // 98

  hipMemsetAsync(deg, 0, (size_t)N_NODES * 4, stream);
  gemm_hist<<<GEMM_BLOCKS + HIST_BLOCKS, 256, 0, stream>>>(
      x, Wl, bl, Wr, br, xl, xr, dst, deg);
  scan1<<<nscan_blocks, 1024, 0, stream>>>(deg, loc, bsum);
  scan2<<<1, 128, 0, stream>>>(bsum, nscan_blocks);
  scatter_kernel<<<(N_EDGES / 4 + 255) / 256, 256, 0, stream>>>(
      src, dst, loc, bsum, csr);
  gat_node<<<(N_NODES * 64 + 255) / 256, 256, 0, stream>>>(
      xl, att, bias, loc, deg, bsum, csr, out);
}

// Round 10
// 491.653 us; speedup vs baseline: 1.0152x; 1.0152x over previous
//
#include <hip/hip_runtime.h>
#include <hip/hip_bf16.h>
#include <cstdint>

#define N_NODES 100000
#define N_EDGES 1600000
#define DIM 128            // HEADS * OUT_C = 4 * 32
#define GR 64              // rows per block in the dual GEMM
#define GEMM_BLOCKS ((N_NODES + GR - 1) / GR)   // 1563 (last block partial)
#define HIST_BLOCKS ((N_EDGES + 255) / 256)     // 6250, one atomic per thread

// branch-free exact LeakyReLU(0.2): v>=0 -> v, v<0 -> 0.2v
__device__ __forceinline__ float lr(float v) { return fmaxf(v, 0.2f * v); }

// ---------------------------------------------------------------------------
// Fused: dual projection + dst histogram (data-independent, co-scheduled).
// GEMM blocks: 64 rows x 256 cols (Wl | Wr). Wave rg handles rows
//   r0=rg*16..+15 (acc[16][4] live in VGPRs) -> each wave reads the full W
//   working set for 16 rows instead of 8, halving L2 W traffic vs R6.
//   x tile (32 KB) staged via coalesced float4; reads are wave-uniform
//   ds_read_b128 broadcasts. W loads: plain loop, compiler-scheduled
//   (explicit prefetch regressed in R9: VGPR 44->60, VALUBusy 36->32).
// Hist blocks: one atomicAdd per thread (R6 form).
// ---------------------------------------------------------------------------
__global__ __launch_bounds__(256) void gemm_hist(
    const float* __restrict__ x,
    const float* __restrict__ Wl, const float* __restrict__ bl,
    const float* __restrict__ Wr, const float* __restrict__ br,
    float* __restrict__ xl, float* __restrict__ xr,
    const int* __restrict__ dst, int* __restrict__ deg) {
  __shared__ float xs[GR][DIM];          // 32 KB (unused by hist blocks)
  const int tid = threadIdx.x;

  if (blockIdx.x >= GEMM_BLOCKS) {       // block-uniform branch
    const int i = (blockIdx.x - GEMM_BLOCKS) * 256 + tid;
    if (i < N_EDGES) atomicAdd(&deg[dst[i]], 1);
    return;
  }

  const int row0 = blockIdx.x * GR;

  // stage x tile: 64 rows * 32 float4 = 2048 float4, 8 per thread, coalesced
#pragma unroll
  for (int i = 0; i < 8; ++i) {
    const int idx = i * 256 + tid;       // 0..2047
    const int r = idx >> 5;              // 32 float4 per row
    const int c4 = idx & 31;
    const int rr = min(row0 + r, N_NODES - 1);   // clamp (tail block)
    const float4 v = *reinterpret_cast<const float4*>(
        x + (size_t)rr * DIM + c4 * 4);
    *reinterpret_cast<float4*>(&xs[r][c4 * 4]) = v;
  }
  __syncthreads();

  const int cg = tid & 63;               // 0..63 column group
  const int rg = tid >> 6;               // 0..3 row group
  const int which = cg >> 5;             // 0 -> Wl, 1 -> Wr
  const int col0 = (cg & 31) * 4;        // 0..124
  const float* __restrict__ W = which ? Wr : Wl;
  const float* __restrict__ b = which ? br : bl;
  float* __restrict__ o = which ? xr : xl;
  const int r0 = rg * 16;

  float acc[16][4];
#pragma unroll
  for (int r = 0; r < 16; ++r)
#pragma unroll
    for (int c = 0; c < 4; ++c) acc[r][c] = 0.f;

  for (int kb = 0; kb < DIM; kb += 4) {
    const float4 w0 = *reinterpret_cast<const float4*>(W + (kb + 0) * DIM + col0);
    const float4 w1 = *reinterpret_cast<const float4*>(W + (kb + 1) * DIM + col0);
    const float4 w2 = *reinterpret_cast<const float4*>(W + (kb + 2) * DIM + col0);
    const float4 w3 = *reinterpret_cast<const float4*>(W + (kb + 3) * DIM + col0);
#pragma unroll
    for (int r = 0; r < 16; ++r) {
      const float4 xv = *reinterpret_cast<const float4*>(&xs[r0 + r][kb]);
      acc[r][0] = fmaf(xv.x, w0.x, acc[r][0]);
      acc[r][1] = fmaf(xv.x, w0.y, acc[r][1]);
      acc[r][2] = fmaf(xv.x, w0.z, acc[r][2]);
      acc[r][3] = fmaf(xv.x, w0.w, acc[r][3]);
      acc[r][0] = fmaf(xv.y, w1.x, acc[r][0]);
      acc[r][1] = fmaf(xv.y, w1.y, acc[r][1]);
      acc[r][2] = fmaf(xv.y, w1.z, acc[r][2]);
      acc[r][3] = fmaf(xv.y, w1.w, acc[r][3]);
      acc[r][0] = fmaf(xv.z, w2.x, acc[r][0]);
      acc[r][1] = fmaf(xv.z, w2.y, acc[r][1]);
      acc[r][2] = fmaf(xv.z, w2.z, acc[r][2]);
      acc[r][3] = fmaf(xv.z, w2.w, acc[r][3]);
      acc[r][0] = fmaf(xv.w, w3.x, acc[r][0]);
      acc[r][1] = fmaf(xv.w, w3.y, acc[r][1]);
      acc[r][2] = fmaf(xv.w, w3.z, acc[r][2]);
      acc[r][3] = fmaf(xv.w, w3.w, acc[r][3]);
    }
  }

  const float4 bb = *reinterpret_cast<const float4*>(b + col0);
#pragma unroll
  for (int r = 0; r < 16; ++r) {
    const int row = row0 + r0 + r;
    if (row < N_NODES) {                 // tail-block guard
      float4 ov;
      ov.x = acc[r][0] + bb.x;
      ov.y = acc[r][1] + bb.y;
      ov.z = acc[r][2] + bb.z;
      ov.w = acc[r][3] + bb.w;
      *reinterpret_cast<float4*>(o + (size_t)row * DIM + col0) = ov;
    }
  }
}

// ---------------------------------------------------------------------------
// CSR build. scan1: per-1024-block local exclusive scan of deg (-> loc) +
// block sums. scan2: exclusive scan of the 98 block sums. scatter and gat
// apply bsum themselves (no scan3).
// ---------------------------------------------------------------------------
__global__ __launch_bounds__(1024) void scan1(const int* __restrict__ deg,
                                              int* __restrict__ loc,
                                              int* __restrict__ bsum) {
  __shared__ int tmp[1024];
  const int tid = threadIdx.x;
  const int gid = blockIdx.x * 1024 + tid;
  const int v = (gid < N_NODES) ? deg[gid] : 0;
  int xacc = v;
  tmp[tid] = v;
  __syncthreads();
  for (int offd = 1; offd < 1024; offd <<= 1) {
    const int t = (tid >= offd) ? tmp[tid - offd] : 0;
    __syncthreads();
    xacc += t;
    tmp[tid] = xacc;
    __syncthreads();
  }
  if (gid < N_NODES) loc[gid] = xacc - v;        // exclusive within block
  if (tid == 1023) bsum[blockIdx.x] = xacc;      // block total
}

__global__ __launch_bounds__(128) void scan2(int* __restrict__ bsum, int nb) {
  __shared__ int tmp[128];
  const int tid = threadIdx.x;
  const int v = (tid < nb) ? bsum[tid] : 0;
  int xacc = v;
  tmp[tid] = v;
  __syncthreads();
  for (int offd = 1; offd < 128; offd <<= 1) {
    const int t = (tid >= offd) ? tmp[tid - offd] : 0;
    __syncthreads();
    xacc += t;
    tmp[tid] = xacc;
    __syncthreads();
  }
  if (tid < nb) bsum[tid] = xacc - v;            // exclusive block offsets
}

// scatter: csr slot = (local excl via atomic) + block offset. After this,
// loc[d] = local_excl[d] + deg[d]  (used by gat to reconstruct beg/end).
__global__ __launch_bounds__(256) void scatter_kernel(const int* __restrict__ src,
                                                      const int* __restrict__ dst,
                                                      int* __restrict__ loc,
                                                      const int* __restrict__ bsum,
                                                      int* __restrict__ csr) {
  const int4* __restrict__ src4 = reinterpret_cast<const int4*>(src);
  const int4* __restrict__ dst4 = reinterpret_cast<const int4*>(dst);
  const int i = blockIdx.x * 256 + threadIdx.x;
  if (i < N_EDGES / 4) {                         // 400000 exact
    const int4 s4 = src4[i];
    const int4 d4 = dst4[i];
    int slot;
    slot = atomicAdd(&loc[d4.x], 1) + bsum[d4.x >> 10];  csr[slot] = s4.x;
    slot = atomicAdd(&loc[d4.y], 1) + bsum[d4.y >> 10];  csr[slot] = s4.y;
    slot = atomicAdd(&loc[d4.z], 1) + bsum[d4.z >> 10];  csr[slot] = s4.z;
    slot = atomicAdd(&loc[d4.w], 1) + bsum[d4.w >> 10];  csr[slot] = s4.w;
  }
}

// ---------------------------------------------------------------------------
// One wave per destination node, 4-way edge packing:
// lane = q*16 + i (q = edge slot 0..3, i = channel group). Lane owns 8
// channels c0 = 8i .. 8i+7, so 16 lanes cover a 128-ch row and the wave
// processes FOUR edges per iteration (slot q handles edges 4j+q of the
// 64-id chunk). Head = 32 ch = 4 lanes -> score reduce is 2 shfl_xor (1,2).
// Four independent online-softmax states (m, l, acc8), merged at the end
// via shfl_xor 16 then 32. Self loop lives in slot 0 only. Invalid slots:
// score -2e30 (< -1e30 empty-state init -> exp underflows to 0) + w=0.
// CSR range from post-scatter loc: end = loc[d]+bsum[d>>10], beg = end-deg[d].
// xr lives in `out` (read before overwrite, same row only).
// ---------------------------------------------------------------------------
__global__ __launch_bounds__(256) void gat_node(
    const float* __restrict__ xl,
    const float* __restrict__ att, const float* __restrict__ bias,
    const int* __restrict__ loc, const int* __restrict__ deg,
    const int* __restrict__ bsum, const int* __restrict__ csr,
    float* __restrict__ out) {
  const int wid = (blockIdx.x * 256 + threadIdx.x) >> 6;
  const int lane = threadIdx.x & 63;
  if (wid >= N_NODES) return;
  const int d = wid;
  const int q = lane >> 4;           // edge slot
  const int i = lane & 15;           // channel group
  const int c0 = i * 8;              // channel base

  const float4 aA = *reinterpret_cast<const float4*>(att + c0);
  const float4 aB = *reinterpret_cast<const float4*>(att + c0 + 4);
  const float4 rA = *reinterpret_cast<const float4*>(out + (size_t)d * DIM + c0);
  const float4 rB = *reinterpret_cast<const float4*>(out + (size_t)d * DIM + c0 + 4);
  const float4 sA = *reinterpret_cast<const float4*>(xl + (size_t)d * DIM + c0);
  const float4 sB = *reinterpret_cast<const float4*>(xl + (size_t)d * DIM + c0 + 4);

  // self-loop score (same value in every slot; only slot 0 keeps the state)
  float p = lr(sA.x + rA.x) * aA.x + lr(sA.y + rA.y) * aA.y
          + lr(sA.z + rA.z) * aA.z + lr(sA.w + rA.w) * aA.w
          + lr(sB.x + rB.x) * aB.x + lr(sB.y + rB.y) * aB.y
          + lr(sB.z + rB.z) * aB.z + lr(sB.w + rB.w) * aB.w;
  p += __shfl_xor(p, 1);
  p += __shfl_xor(p, 2);             // 4-lane head group holds its score

  const bool q0 = (q == 0);
  float m = q0 ? p : -1e30f;         // running max
  float l = q0 ? 1.f : 0.f;          // running denom
  float4 cA, cB;                     // running weighted message sum
  cA.x = q0 ? sA.x : 0.f;  cA.y = q0 ? sA.y : 0.f;
  cA.z = q0 ? sA.z : 0.f;  cA.w = q0 ? sA.w : 0.f;
  cB.x = q0 ? sB.x : 0.f;  cB.y = q0 ? sB.y : 0.f;
  cB.z = q0 ? sB.z : 0.f;  cB.w = q0 ? sB.w : 0.f;

  const int dg = deg[d];
  const int end = loc[d] + bsum[d >> 10];   // loc[d] = local_excl + deg (post-scatter)
  const int beg = end - dg;

  for (int cbase = beg; cbase < end; cbase += 64) {
    const int idx = cbase + lane;
    const int sv = csr[idx < end ? idx : end - 1];   // 64 edge ids, coalesced
    const int cnt = min(64, end - cbase);
    const int nj = (cnt + 3) >> 2;   // iterations; slot q handles edges 4j+q

    // prefetch j=0: slot q's first edge id is at position q
    const int s0 = __shfl(sv, q);
    const float* rp0 = xl + (size_t)s0 * DIM + c0;
    float4 nA = *reinterpret_cast<const float4*>(rp0);
    float4 nB = *reinterpret_cast<const float4*>(rp0 + 4);

    for (int j = 0; j < nj; ++j) {
      const float4 xA = nA;
      const float4 xB = nB;
      if (j + 1 < nj) {
        const int s1 = __shfl(sv, 4 * (j + 1) + q);  // <= 63 always
        const float* rp = xl + (size_t)s1 * DIM + c0;
        nA = *reinterpret_cast<const float4*>(rp);
        nB = *reinterpret_cast<const float4*>(rp + 4);
      }
      const bool valid = (4 * j + q) < cnt;

      float ek = lr(xA.x + rA.x) * aA.x + lr(xA.y + rA.y) * aA.y
               + lr(xA.z + rA.z) * aA.z + lr(xA.w + rA.w) * aA.w
               + lr(xB.x + rB.x) * aB.x + lr(xB.y + rB.y) * aB.y
               + lr(xB.z + rB.z) * aB.z + lr(xB.w + rB.w) * aB.w;
      ek += __shfl_xor(ek, 1);
      ek += __shfl_xor(ek, 2);
      ek = valid ? ek : -2e30f;

      const float mn = fmaxf(m, ek);
      const float sc = __expf(m - mn);
      float w = __expf(ek - mn);
      w = valid ? w : 0.f;
      l = l * sc + w;
      cA.x = fmaf(cA.x, sc, w * xA.x);
      cA.y = fmaf(cA.y, sc, w * xA.y);
      cA.z = fmaf(cA.z, sc, w * xA.z);
      cA.w = fmaf(cA.w, sc, w * xA.w);
      cB.x = fmaf(cB.x, sc, w * xB.x);
      cB.y = fmaf(cB.y, sc, w * xB.y);
      cB.z = fmaf(cB.z, sc, w * xB.z);
      cB.w = fmaf(cB.w, sc, w * xB.w);
      m = mn;
    }
  }

  // merge the four slots' states: xor 16 (q0<->q1, q2<->q3), then xor 32
  auto merge = [&](int mask) {
    const float mo = __shfl_xor(m, mask);
    const float lo = __shfl_xor(l, mask);
    float4 oA, oB;
    oA.x = __shfl_xor(cA.x, mask);  oA.y = __shfl_xor(cA.y, mask);
    oA.z = __shfl_xor(cA.z, mask);  oA.w = __shfl_xor(cA.w, mask);
    oB.x = __shfl_xor(cB.x, mask);  oB.y = __shfl_xor(cB.y, mask);
    oB.z = __shfl_xor(cB.z, mask);  oB.w = __shfl_xor(cB.w, mask);
    const float ms = fmaxf(m, mo);
    const float w1 = __expf(m - ms);
    const float w2 = __expf(mo - ms);
    l = l * w1 + lo * w2;
    cA.x = cA.x * w1 + oA.x * w2;  cA.y = cA.y * w1 + oA.y * w2;
    cA.z = cA.z * w1 + oA.z * w2;  cA.w = cA.w * w1 + oA.w * w2;
    cB.x = cB.x * w1 + oB.x * w2;  cB.y = cB.y * w1 + oB.y * w2;
    cB.z = cB.z * w1 + oB.z * w2;  cB.w = cB.w * w1 + oB.w * w2;
    m = ms;
  };
  merge(16);
  merge(32);

  if (lane < 16) {                   // slot 0 writes the result
    const float inv = 1.f / l;       // l >= e^{p - m*} > 0 (self loop)
    const float4 bA = *reinterpret_cast<const float4*>(bias + c0);
    const float4 bB = *reinterpret_cast<const float4*>(bias + c0 + 4);
    float4 oA, oB;
    oA.x = cA.x * inv + bA.x;  oA.y = cA.y * inv + bA.y;
    oA.z = cA.z * inv + bA.z;  oA.w = cA.w * inv + bA.w;
    oB.x = cB.x * inv + bB.x;  oB.y = cB.y * inv + bB.y;
    oB.z = cB.z * inv + bB.z;  oB.w = cB.w * inv + bB.w;
    *reinterpret_cast<float4*>(out + (size_t)d * DIM + c0) = oA;
    *reinterpret_cast<float4*>(out + (size_t)d * DIM + c0 + 4) = oB;
  }
}

// ---------------------------------------------------------------------------
extern "C" void kernel_launch(void* const* d_in, const int* in_sizes, int n_in,
                              void* d_out, int out_size, void* d_ws, size_t ws_size,
                              hipStream_t stream) {
  const float* x    = (const float*)d_in[0];
  const float* Wl   = (const float*)d_in[1];
  const float* bl   = (const float*)d_in[2];
  const float* Wr   = (const float*)d_in[3];
  const float* br   = (const float*)d_in[4];
  const float* att  = (const float*)d_in[5];
  const float* bias = (const float*)d_in[6];
  const int* src    = (const int*)d_in[7];
  const int* dst    = (const int*)d_in[8];
  float* out = (float*)d_out;

  char* w = (char*)d_ws;
  size_t off = 0;
  auto alloc = [&](size_t bytes) -> void* {
    void* p = w + off;
    off = (off + bytes + 255) & ~(size_t)255;
    return p;
  };
  float* xl = (float*)alloc((size_t)N_NODES * DIM * 4);   // 51.2 MB
  int* deg  = (int*)alloc((size_t)N_NODES * 4);
  int* loc  = (int*)alloc((size_t)N_NODES * 4);
  int* bsum = (int*)alloc(1024);
  int* csr  = (int*)alloc((size_t)N_EDGES * 4);           // 6.4 MB
  float* xr = out;                                        // scratch alias (safe: see gat_node)

  const int nscan_blocks = (N_NODES + 1023) / 1024;   // 98

  hipMemsetAsync(deg, 0, (size_t)N_NODES * 4, stream);
  gemm_hist<<<GEMM_BLOCKS + HIST_BLOCKS, 256, 0, stream>>>(
      x, Wl, bl, Wr, br, xl, xr, dst, deg);
  scan1<<<nscan_blocks, 1024, 0, stream>>>(deg, loc, bsum);
  scan2<<<1, 128, 0, stream>>>(bsum, nscan_blocks);
  scatter_kernel<<<(N_EDGES / 4 + 255) / 256, 256, 0, stream>>>(
      src, dst, loc, bsum, csr);
  gat_node<<<(N_NODES * 64 + 255) / 256, 256, 0, stream>>>(
      xl, att, bias, loc, deg, bsum, csr, out);
}